// Round 1
// baseline (13410.738 us; speedup 1.0000x reference)
//
#include <hip/hip_runtime.h>
#include <math.h>

#define TSEQ 512
#define HDIM 512
#define EDIM 512
#define NB   32
#define ROWS 64
#define GATES 2048
#define NEGV -1000000000.0f

__device__ __forceinline__ float sigf(float x){ return 1.0f/(1.0f + __expf(-x)); }

// table[v][j] = sum_k emb[v][k] * W_ih[k][j] + b_lstm[j]
__global__ __launch_bounds__(256) void table_k(const float* __restrict__ emb,
        const float* __restrict__ W_ih, const float* __restrict__ b_lstm,
        float* __restrict__ table){
  int j = blockIdx.x*256 + threadIdx.x;
  int v = blockIdx.y;
  float acc = b_lstm[j];
  #pragma unroll 4
  for(int k=0;k<EDIM;k++) acc = fmaf(emb[v*EDIM+k], W_ih[(size_t)k*GATES+j], acc);
  table[(size_t)v*GATES+j] = acc;
}

// One LSTM time step for all 64 stacked rows (x batches 0..31, y batches 32..63).
// grid: (512/64 jblocks, 64/4 rowblocks) = (8,16), 256 threads.
__global__ __launch_bounds__(256) void lstm_step(const int* __restrict__ x, const int* __restrict__ y,
        const float* __restrict__ table, const float* __restrict__ W_hh,
        const float* __restrict__ hsr, float* __restrict__ hs, float* __restrict__ cbuf, int s){
  __shared__ float z_lds[4][4][64];
  int j0 = blockIdx.x*64;
  int r0 = blockIdx.y*4;
  int tid = threadIdx.x;
  const float* hprev = hsr + (size_t)s*ROWS*HDIM + (size_t)r0*HDIM;  // 4 rows x 512, uniform base
  int g  = tid>>6;     // gate 0..3
  int jj = tid&63;     // hidden within block
  int c  = g*HDIM + j0 + jj;   // column of W_hh, all 256 distinct, coalesced per gate group
  float a0=0.f,a1=0.f,a2=0.f,a3=0.f;
  const float* wp = W_hh + c;
  #pragma unroll 8
  for(int k=0;k<HDIM;k++){
    float w = wp[(size_t)k*GATES];
    a0 = fmaf(hprev[k],        w, a0);
    a1 = fmaf(hprev[HDIM+k],   w, a1);
    a2 = fmaf(hprev[2*HDIM+k], w, a2);
    a3 = fmaf(hprev[3*HDIM+k], w, a3);
  }
  z_lds[0][g][jj]=a0; z_lds[1][g][jj]=a1; z_lds[2][g][jj]=a2; z_lds[3][g][jj]=a3;
  __syncthreads();
  // phase 2: gate combine, 256 threads = 4 rows x 64 hidden
  int rl = tid>>6;
  int jl = tid&63;
  int row = r0+rl;
  int tok = (row<NB) ? x[row*TSEQ+s] : y[(row-NB)*TSEQ+s];
  const float* tb = table + (size_t)tok*GATES + j0;
  float zi = z_lds[rl][0][jl] + tb[jl];
  float zf = z_lds[rl][1][jl] + tb[HDIM+jl];
  float zg = z_lds[rl][2][jl] + tb[2*HDIM+jl];
  float zo = z_lds[rl][3][jl] + tb[3*HDIM+jl];
  size_t ci = (size_t)row*HDIM + j0 + jl;
  float cold = cbuf[ci];
  float cn = sigf(zf)*cold + sigf(zi)*tanhf(zg);
  float hn = sigf(zo)*tanhf(cn);
  cbuf[ci] = cn;
  hs[(size_t)(s+1)*ROWS*HDIM + ci] = hn;
}

#define GT 64
#define KT 16
// z[m][n] = sum_k hs[t+1][r][k]*W_out[k][n] + b_out[n],  m = r*512+t, layout z[m*512+n]
__global__ __launch_bounds__(256) void zproj_k(const float* __restrict__ hs,
        const float* __restrict__ W_out, const float* __restrict__ b_out, float* __restrict__ z){
  __shared__ float As[KT][GT+4];
  __shared__ float Bs[KT][GT+4];
  int m0 = blockIdx.x*GT;
  int n0 = blockIdx.y*GT;
  int tid = threadIdx.x;
  int tm = tid&15, tn = tid>>4;
  float acc[4][4];
  #pragma unroll
  for(int i=0;i<4;i++)
    #pragma unroll
    for(int j=0;j<4;j++) acc[i][j]=0.f;
  for(int k0=0;k0<HDIM;k0+=KT){
    {
      int mloc = tid>>2;
      int kloc = (tid&3)*4;
      int m = m0 + mloc;
      int t = m&511, r = m>>9;
      const float4 av = *(const float4*)&hs[(size_t)(t+1)*ROWS*HDIM + (size_t)r*HDIM + k0 + kloc];
      As[kloc+0][mloc]=av.x; As[kloc+1][mloc]=av.y; As[kloc+2][mloc]=av.z; As[kloc+3][mloc]=av.w;
    }
    {
      int kloc = tid>>4;
      int nloc = (tid&15)*4;
      *(float4*)&Bs[kloc][nloc] = *(const float4*)&W_out[(size_t)(k0+kloc)*EDIM + n0 + nloc];
    }
    __syncthreads();
    #pragma unroll
    for(int kk=0;kk<KT;kk++){
      float4 av = *(const float4*)&As[kk][tm*4];
      float4 bv = *(const float4*)&Bs[kk][tn*4];
      float a[4] = {av.x,av.y,av.z,av.w};
      float b[4] = {bv.x,bv.y,bv.z,bv.w};
      #pragma unroll
      for(int i=0;i<4;i++)
        #pragma unroll
        for(int j=0;j<4;j++) acc[i][j] = fmaf(a[i], b[j], acc[i][j]);
    }
    __syncthreads();
  }
  #pragma unroll
  for(int i=0;i<4;i++){
    int m = m0 + tm*4 + i;
    #pragma unroll
    for(int j=0;j<4;j++){
      int n = n0 + tn*4 + j;
      z[(size_t)m*EDIM + n] = acc[i][j] + b_out[n];
    }
  }
}

// theta[b][i][j] = sum_e z[b*512+i][e] * z[(b+32)*512+j][e]   (NT gemm)
__global__ __launch_bounds__(256) void theta_k(const float* __restrict__ z, float* __restrict__ theta){
  __shared__ float As[KT][GT+4];
  __shared__ float Bs[KT][GT+4];
  int m0 = blockIdx.x*GT;
  int n0 = blockIdx.y*GT;
  int b  = blockIdx.z;
  int tid = threadIdx.x;
  int tm = tid&15, tn = tid>>4;
  float acc[4][4];
  #pragma unroll
  for(int i=0;i<4;i++)
    #pragma unroll
    for(int j=0;j<4;j++) acc[i][j]=0.f;
  for(int k0=0;k0<EDIM;k0+=KT){
    {
      int mloc = tid>>2;
      int kloc = (tid&3)*4;
      const float4 av = *(const float4*)&z[((size_t)b*TSEQ + m0+mloc)*EDIM + k0 + kloc];
      As[kloc+0][mloc]=av.x; As[kloc+1][mloc]=av.y; As[kloc+2][mloc]=av.z; As[kloc+3][mloc]=av.w;
    }
    {
      int nloc = tid>>2;
      int kloc = (tid&3)*4;
      const float4 bv = *(const float4*)&z[((size_t)(b+NB)*TSEQ + n0+nloc)*EDIM + k0 + kloc];
      Bs[kloc+0][nloc]=bv.x; Bs[kloc+1][nloc]=bv.y; Bs[kloc+2][nloc]=bv.z; Bs[kloc+3][nloc]=bv.w;
    }
    __syncthreads();
    #pragma unroll
    for(int kk=0;kk<KT;kk++){
      float4 av = *(const float4*)&As[kk][tm*4];
      float4 bv = *(const float4*)&Bs[kk][tn*4];
      float a[4] = {av.x,av.y,av.z,av.w};
      float b2[4] = {bv.x,bv.y,bv.z,bv.w};
      #pragma unroll
      for(int i=0;i<4;i++)
        #pragma unroll
        for(int j=0;j<4;j++) acc[i][j] = fmaf(a[i], b2[j], acc[i][j]);
    }
    __syncthreads();
  }
  #pragma unroll
  for(int i=0;i<4;i++){
    int m = m0 + tm*4 + i;
    #pragma unroll
    for(int j=0;j<4;j++){
      int n = n0 + tn*4 + j;
      theta[((size_t)b*TSEQ + m)*TSEQ + n] = acc[i][j];
    }
  }
}

__global__ __launch_bounds__(256) void mean_k(const float* __restrict__ z, float* __restrict__ zmean){
  int r = blockIdx.x;
  int tid = threadIdx.x;
  for(int ee=tid; ee<EDIM; ee+=256){
    float acc=0.f;
    for(int t=0;t<TSEQ;t++) acc += z[((size_t)r*TSEQ+t)*EDIM+ee];
    zmean[(size_t)r*EDIM+ee] = acc*(1.0f/TSEQ);
  }
}

__global__ __launch_bounds__(256) void gap_k(const float* __restrict__ zmean,
        const float* __restrict__ W_gap, const float* __restrict__ b_gap, float* __restrict__ Aout){
  __shared__ float red[256];
  int b = blockIdx.x;
  int tid = threadIdx.x;
  float acc=0.f;
  for(int i=tid;i<2*EDIM;i+=256){
    float m = (i<EDIM)? zmean[(size_t)b*EDIM+i] : zmean[(size_t)(b+NB)*EDIM + (i-EDIM)];
    acc = fmaf(m, W_gap[i], acc);
  }
  red[tid]=acc; __syncthreads();
  for(int s=128;s>0;s>>=1){ if(tid<s) red[tid]+=red[tid+s]; __syncthreads(); }
  if(tid==0) Aout[b] = red[0] + b_gap[0];
}

// Needleman-Wunsch: one wave (64 lanes) per batch; 8 DP cells per lane in registers.
__global__ __launch_bounds__(64) void nw_k(const float* __restrict__ theta,
        const float* __restrict__ Aout, float* __restrict__ out){
  const float L2E = 1.4426950408889634f, LN2 = 0.6931471805599453f;
  int b = blockIdx.x;
  int lane = threadIdx.x;
  float A = Aout[b];
  float p1[8], p2[8];
  #pragma unroll
  for(int i=0;i<8;i++){ p1[i]=NEGV; p2[i]=NEGV; }
  float p1_0 = NEGV, p2_0 = 0.0f;   // DP cell i=0: d0[0]=0, d1[0]=NEG
  const float* th = theta + (size_t)b*TSEQ*TSEQ;
  for(int k=2;k<=1024;k++){
    float pm1 = __shfl_up(p1[7],1);
    float pm2 = __shfl_up(p2[7],1);
    if(lane==0){ pm1 = p1_0; pm2 = p2_0; }
    float td[8];
    #pragma unroll
    for(int cx=0;cx<8;cx++){
      int i = lane*8+1+cx;
      int j = k-i;
      int jc = j<1?1:(j>512?512:j);
      td[cx] = th[(size_t)(i-1)*TSEQ + (jc-1)];
    }
    float cur[8];
    #pragma unroll
    for(int cx=0;cx<8;cx++){
      int i = lane*8+1+cx;
      int j = k-i;
      bool valid = (j>=1)&&(j<=512);
      float a  = (cx==0? pm1 : p1[cx-1]) + A;
      float bb = (cx==0? pm2 : p2[cx-1]);
      float cc = p1[cx] + A;
      float m = fmaxf(fmaxf(a,bb),cc);
      float s = exp2f((a-m)*L2E) + exp2f((bb-m)*L2E) + exp2f((cc-m)*L2E);
      float v = m + log2f(s)*LN2;
      cur[cx] = valid ? td[cx] + v : NEGV;
    }
    #pragma unroll
    for(int cx=0;cx<8;cx++){ p2[cx]=p1[cx]; p1[cx]=cur[cx]; }
    p2_0 = p1_0; p1_0 = NEGV;
  }
  if(lane==63) out[b] = p1[7];
}

extern "C" void kernel_launch(void* const* d_in, const int* in_sizes, int n_in,
                              void* d_out, int out_size, void* d_ws, size_t ws_size,
                              hipStream_t stream) {
  (void)in_sizes; (void)n_in; (void)out_size; (void)ws_size;
  const int*   x      = (const int*)d_in[0];
  const int*   y      = (const int*)d_in[1];
  const float* emb    = (const float*)d_in[2];
  const float* W_ih   = (const float*)d_in[3];
  const float* W_hh   = (const float*)d_in[4];
  const float* b_lstm = (const float*)d_in[5];
  const float* W_out  = (const float*)d_in[6];
  const float* b_out  = (const float*)d_in[7];
  const float* W_gap  = (const float*)d_in[8];
  const float* b_gap  = (const float*)d_in[9];
  float* out = (float*)d_out;

  char* ws = (char*)d_ws;
  const size_t OFF_TABLE = 0;                       // 22*2048*4 = 180224
  const size_t OFF_HS    = 184320;                  // 513*64*512*4 = 67239936
  const size_t OFF_CBUF  = OFF_HS + 67239936;       // 131072
  const size_t OFF_Z     = OFF_CBUF + 131072;       // 64*512*512*4 = 67108864
  const size_t OFF_THETA = OFF_Z + 67108864;        // 32*512*512*4 = 33554432
  const size_t OFF_ZMEAN = OFF_THETA + 33554432;    // 131072
  const size_t OFF_AOUT  = OFF_ZMEAN + 131072;      // 128
  float* table = (float*)(ws + OFF_TABLE);
  float* hs    = (float*)(ws + OFF_HS);
  float* cbuf  = (float*)(ws + OFF_CBUF);
  float* z     = (float*)(ws + OFF_Z);
  float* theta = (float*)(ws + OFF_THETA);
  float* zmean = (float*)(ws + OFF_ZMEAN);
  float* Aout  = (float*)(ws + OFF_AOUT);

  // zero h_0 and c_0
  hipMemsetAsync(hs,   0, (size_t)ROWS*HDIM*sizeof(float), stream);
  hipMemsetAsync(cbuf, 0, (size_t)ROWS*HDIM*sizeof(float), stream);

  table_k<<<dim3(8,22), 256, 0, stream>>>(emb, W_ih, b_lstm, table);
  for(int s=0;s<TSEQ;s++)
    lstm_step<<<dim3(8,16), 256, 0, stream>>>(x, y, table, W_hh, hs, hs, cbuf, s);
  zproj_k<<<dim3(512,8), 256, 0, stream>>>(hs, W_out, b_out, z);
  theta_k<<<dim3(8,8,32), 256, 0, stream>>>(z, theta);
  mean_k<<<64, 256, 0, stream>>>(z, zmean);
  gap_k<<<32, 256, 0, stream>>>(zmean, W_gap, b_gap, Aout);
  nw_k<<<32, 64, 0, stream>>>(theta, Aout, out);
}

// Round 2
// 4170.111 us; speedup vs baseline: 3.2159x; 3.2159x over previous
//
#include <hip/hip_runtime.h>
#include <math.h>

#define TSEQ 512
#define HDIM 512
#define EDIM 512
#define NB   32
#define ROWS 64
#define GATES 2048
#define NEGV -1000000000.0f

typedef __attribute__((ext_vector_type(8))) short bf16x8;
typedef __attribute__((ext_vector_type(4))) float f32x4;

__device__ __forceinline__ float sigf(float x){ return 1.0f/(1.0f + __expf(-x)); }

__device__ __forceinline__ unsigned short f2bf(float f){
  unsigned int u = __builtin_bit_cast(unsigned int, f);
  unsigned int r = (u + 0x7fff + ((u>>16)&1)) >> 16;
  return (unsigned short)r;
}

// table[v][j] = sum_k emb[v][k] * W_ih[k][j] + b_lstm[j]   (fp32)
__global__ __launch_bounds__(256) void table_k(const float* __restrict__ emb,
        const float* __restrict__ W_ih, const float* __restrict__ b_lstm,
        float* __restrict__ table){
  int j = blockIdx.x*256 + threadIdx.x;
  int v = blockIdx.y;
  float acc = b_lstm[j];
  #pragma unroll 4
  for(int k=0;k<EDIM;k++) acc = fmaf(emb[v*EDIM+k], W_ih[(size_t)k*GATES+j], acc);
  table[(size_t)v*GATES+j] = acc;
}

// Pre-swizzle W_hh (512 x 2048 fp32) into bf16 B-fragment order for
// mfma_f32_16x16x32_bf16. chunk cid = wg*64 + g*16 + kc; lane l holds
// B[kc*32 + (l>>4)*8 + e][g*512 + wg*16 + (l&15)], e=0..7.
__global__ __launch_bounds__(64) void wprep_k(const float* __restrict__ W_hh,
        unsigned short* __restrict__ Wswz){
  int cid = blockIdx.x;           // 0..2047
  int lane = threadIdx.x;         // 0..63
  int wg = cid>>6, g = (cid>>4)&3, kc = cid&15;
  int col = g*512 + wg*16 + (lane&15);
  int kbase = kc*32 + (lane>>4)*8;
  unsigned short v[8];
  #pragma unroll
  for(int e=0;e<8;e++) v[e] = f2bf(W_hh[(size_t)(kbase+e)*GATES + col]);
  *(uint4*)&Wswz[((size_t)cid*64 + lane)*8] = *(const uint4*)v;
}

// One LSTM step. 32 WGs x 512 threads (8 waves). WG wg owns hidden units
// jglob = wg*16 .. +16 (x4 gates = 64 output cols), all 64 rows.
// h stored bf16 in A-fragment-swizzled layout, double-buffered.
__global__ __launch_bounds__(512) void lstm_mfma(const int* __restrict__ x, const int* __restrict__ y,
        const float* __restrict__ table, const unsigned short* __restrict__ Wswz,
        const unsigned short* __restrict__ h_in, unsigned short* __restrict__ h_out,
        float* __restrict__ c_buf, float* __restrict__ hs, int s){
  __shared__ unsigned short hA[32768];   // 64KB  [mt][kc][lane][8]
  __shared__ unsigned short wB[32768];   // 64KB  [g][kc][lane][8]
  __shared__ float zx[4][64][17];        // gate exchange, padded
  int tid = threadIdx.x;
  int wg  = blockIdx.x;

  // stage h and this WG's W slab into LDS (linear float4 copies)
  {
    const float4* hg = (const float4*)h_in;
    float4* hl = (float4*)hA;
    const float4* wgp = (const float4*)(Wswz + (size_t)wg*32768);
    float4* wl = (float4*)wB;
    #pragma unroll
    for(int i=0;i<8;i++){
      hl[tid + i*512] = hg[tid + i*512];
      wl[tid + i*512] = wgp[tid + i*512];
    }
  }
  __syncthreads();

  int wv = tid>>6, lane = tid&63;
  int g = wv>>1, mh = wv&1;
  f32x4 acc0 = {0.f,0.f,0.f,0.f};
  f32x4 acc1 = {0.f,0.f,0.f,0.f};
  #pragma unroll
  for(int kc=0;kc<16;kc++){
    bf16x8 b  = *(const bf16x8*)(const void*)&wB[((g*16+kc)*64 + lane)*8];
    bf16x8 a0 = *(const bf16x8*)(const void*)&hA[(((mh*2  )*16+kc)*64 + lane)*8];
    bf16x8 a1 = *(const bf16x8*)(const void*)&hA[(((mh*2+1)*16+kc)*64 + lane)*8];
    acc0 = __builtin_amdgcn_mfma_f32_16x16x32_bf16(a0,b,acc0,0,0,0);
    acc1 = __builtin_amdgcn_mfma_f32_16x16x32_bf16(a1,b,acc1,0,0,0);
  }
  #pragma unroll
  for(int q=0;q<4;q++){
    zx[g][(mh*2  )*16 + (lane>>4)*4 + q][lane&15] = acc0[q];
    zx[g][(mh*2+1)*16 + (lane>>4)*4 + q][lane&15] = acc1[q];
  }
  __syncthreads();

  // gate combine: thread handles cells (row, jb) and (row, jb+1)
  int row = tid>>3, jb = (tid&7)*2;
  int tok = (row<NB) ? x[row*TSEQ+s] : y[(row-NB)*TSEQ+s];
  const float* tbl = table + (size_t)tok*GATES;
  #pragma unroll
  for(int u=0;u<2;u++){
    int jj = jb+u;
    int jglob = wg*16 + jj;
    float zi  = zx[0][row][jj] + tbl[jglob];
    float zf  = zx[1][row][jj] + tbl[512+jglob];
    float zg_ = zx[2][row][jj] + tbl[1024+jglob];
    float zo  = zx[3][row][jj] + tbl[1536+jglob];
    int ci = wg*1024 + row*16 + jj;
    float c  = c_buf[ci];
    float cn = sigf(zf)*c + sigf(zi)*tanhf(zg_);
    float hn = sigf(zo)*tanhf(cn);
    c_buf[ci] = cn;
    hs[(size_t)s*(ROWS*HDIM) + row*HDIM + jglob] = hn;   // h(s+1) stored at slab s
    int mt=row>>4, kc=jglob>>5, ln=(row&15)|(((jglob>>3)&3)<<4), e=jglob&7;
    h_out[((mt*16+kc)*64+ln)*8 + e] = f2bf(hn);
  }
}

#define GT 64
#define KT 16
// z[m][n], m = r*512 + t; reads hs slab t (holds h(t+1))
__global__ __launch_bounds__(256) void zproj_k(const float* __restrict__ hs,
        const float* __restrict__ W_out, const float* __restrict__ b_out, float* __restrict__ z){
  __shared__ float As[KT][GT+4];
  __shared__ float Bs[KT][GT+4];
  int m0 = blockIdx.x*GT;
  int n0 = blockIdx.y*GT;
  int tid = threadIdx.x;
  int tm = tid&15, tn = tid>>4;
  float acc[4][4];
  #pragma unroll
  for(int i=0;i<4;i++)
    #pragma unroll
    for(int j=0;j<4;j++) acc[i][j]=0.f;
  for(int k0=0;k0<HDIM;k0+=KT){
    {
      int mloc = tid>>2;
      int kloc = (tid&3)*4;
      int m = m0 + mloc;
      int t = m&511, r = m>>9;
      const float4 av = *(const float4*)&hs[(size_t)t*ROWS*HDIM + (size_t)r*HDIM + k0 + kloc];
      As[kloc+0][mloc]=av.x; As[kloc+1][mloc]=av.y; As[kloc+2][mloc]=av.z; As[kloc+3][mloc]=av.w;
    }
    {
      int kloc = tid>>4;
      int nloc = (tid&15)*4;
      *(float4*)&Bs[kloc][nloc] = *(const float4*)&W_out[(size_t)(k0+kloc)*EDIM + n0 + nloc];
    }
    __syncthreads();
    #pragma unroll
    for(int kk=0;kk<KT;kk++){
      float4 av = *(const float4*)&As[kk][tm*4];
      float4 bv = *(const float4*)&Bs[kk][tn*4];
      float a[4] = {av.x,av.y,av.z,av.w};
      float b[4] = {bv.x,bv.y,bv.z,bv.w};
      #pragma unroll
      for(int i=0;i<4;i++)
        #pragma unroll
        for(int j=0;j<4;j++) acc[i][j] = fmaf(a[i], b[j], acc[i][j]);
    }
    __syncthreads();
  }
  #pragma unroll
  for(int i=0;i<4;i++){
    int m = m0 + tm*4 + i;
    #pragma unroll
    for(int j=0;j<4;j++){
      int n = n0 + tn*4 + j;
      z[(size_t)m*EDIM + n] = acc[i][j] + b_out[n];
    }
  }
}

// theta[b][i][j] = sum_e z[b*512+i][e] * z[(b+32)*512+j][e]   (NT gemm)
__global__ __launch_bounds__(256) void theta_k(const float* __restrict__ z, float* __restrict__ theta){
  __shared__ float As[KT][GT+4];
  __shared__ float Bs[KT][GT+4];
  int m0 = blockIdx.x*GT;
  int n0 = blockIdx.y*GT;
  int b  = blockIdx.z;
  int tid = threadIdx.x;
  int tm = tid&15, tn = tid>>4;
  float acc[4][4];
  #pragma unroll
  for(int i=0;i<4;i++)
    #pragma unroll
    for(int j=0;j<4;j++) acc[i][j]=0.f;
  for(int k0=0;k0<EDIM;k0+=KT){
    {
      int mloc = tid>>2;
      int kloc = (tid&3)*4;
      const float4 av = *(const float4*)&z[((size_t)b*TSEQ + m0+mloc)*EDIM + k0 + kloc];
      As[kloc+0][mloc]=av.x; As[kloc+1][mloc]=av.y; As[kloc+2][mloc]=av.z; As[kloc+3][mloc]=av.w;
    }
    {
      int nloc = tid>>2;
      int kloc = (tid&3)*4;
      const float4 bv = *(const float4*)&z[((size_t)(b+NB)*TSEQ + n0+nloc)*EDIM + k0 + kloc];
      Bs[kloc+0][nloc]=bv.x; Bs[kloc+1][nloc]=bv.y; Bs[kloc+2][nloc]=bv.z; Bs[kloc+3][nloc]=bv.w;
    }
    __syncthreads();
    #pragma unroll
    for(int kk=0;kk<KT;kk++){
      float4 av = *(const float4*)&As[kk][tm*4];
      float4 bv = *(const float4*)&Bs[kk][tn*4];
      float a[4] = {av.x,av.y,av.z,av.w};
      float b2[4] = {bv.x,bv.y,bv.z,bv.w};
      #pragma unroll
      for(int i=0;i<4;i++)
        #pragma unroll
        for(int j=0;j<4;j++) acc[i][j] = fmaf(a[i], b2[j], acc[i][j]);
    }
    __syncthreads();
  }
  #pragma unroll
  for(int i=0;i<4;i++){
    int m = m0 + tm*4 + i;
    #pragma unroll
    for(int j=0;j<4;j++){
      int n = n0 + tn*4 + j;
      theta[((size_t)b*TSEQ + m)*TSEQ + n] = acc[i][j];
    }
  }
}

__global__ __launch_bounds__(256) void mean_k(const float* __restrict__ z, float* __restrict__ zmean){
  int r = blockIdx.x;
  int tid = threadIdx.x;
  for(int ee=tid; ee<EDIM; ee+=256){
    float acc=0.f;
    for(int t=0;t<TSEQ;t++) acc += z[((size_t)r*TSEQ+t)*EDIM+ee];
    zmean[(size_t)r*EDIM+ee] = acc*(1.0f/TSEQ);
  }
}

__global__ __launch_bounds__(256) void gap_k(const float* __restrict__ zmean,
        const float* __restrict__ W_gap, const float* __restrict__ b_gap, float* __restrict__ Aout){
  __shared__ float red[256];
  int b = blockIdx.x;
  int tid = threadIdx.x;
  float acc=0.f;
  for(int i=tid;i<2*EDIM;i+=256){
    float m = (i<EDIM)? zmean[(size_t)b*EDIM+i] : zmean[(size_t)(b+NB)*EDIM + (i-EDIM)];
    acc = fmaf(m, W_gap[i], acc);
  }
  red[tid]=acc; __syncthreads();
  for(int s=128;s>0;s>>=1){ if(tid<s) red[tid]+=red[tid+s]; __syncthreads(); }
  if(tid==0) Aout[b] = red[0] + b_gap[0];
}

// Needleman-Wunsch: one wave per batch; 8 DP cells per lane in registers.
__global__ __launch_bounds__(64) void nw_k(const float* __restrict__ theta,
        const float* __restrict__ Aout, float* __restrict__ out){
  const float L2E = 1.4426950408889634f, LN2 = 0.6931471805599453f;
  int b = blockIdx.x;
  int lane = threadIdx.x;
  float A = Aout[b];
  float p1[8], p2[8];
  #pragma unroll
  for(int i=0;i<8;i++){ p1[i]=NEGV; p2[i]=NEGV; }
  float p1_0 = NEGV, p2_0 = 0.0f;
  const float* th = theta + (size_t)b*TSEQ*TSEQ;
  for(int k=2;k<=1024;k++){
    float pm1 = __shfl_up(p1[7],1);
    float pm2 = __shfl_up(p2[7],1);
    if(lane==0){ pm1 = p1_0; pm2 = p2_0; }
    float td[8];
    #pragma unroll
    for(int cx=0;cx<8;cx++){
      int i = lane*8+1+cx;
      int j = k-i;
      int jc = j<1?1:(j>512?512:j);
      td[cx] = th[(size_t)(i-1)*TSEQ + (jc-1)];
    }
    float cur[8];
    #pragma unroll
    for(int cx=0;cx<8;cx++){
      int i = lane*8+1+cx;
      int j = k-i;
      bool valid = (j>=1)&&(j<=512);
      float a  = (cx==0? pm1 : p1[cx-1]) + A;
      float bb = (cx==0? pm2 : p2[cx-1]);
      float cc = p1[cx] + A;
      float m = fmaxf(fmaxf(a,bb),cc);
      float sum = exp2f((a-m)*L2E) + exp2f((bb-m)*L2E) + exp2f((cc-m)*L2E);
      float v = m + log2f(sum)*LN2;
      cur[cx] = valid ? td[cx] + v : NEGV;
    }
    #pragma unroll
    for(int cx=0;cx<8;cx++){ p2[cx]=p1[cx]; p1[cx]=cur[cx]; }
    p2_0 = p1_0; p1_0 = NEGV;
  }
  if(lane==63) out[b] = p1[7];
}

extern "C" void kernel_launch(void* const* d_in, const int* in_sizes, int n_in,
                              void* d_out, int out_size, void* d_ws, size_t ws_size,
                              hipStream_t stream) {
  (void)in_sizes; (void)n_in; (void)out_size; (void)ws_size;
  const int*   x      = (const int*)d_in[0];
  const int*   y      = (const int*)d_in[1];
  const float* emb    = (const float*)d_in[2];
  const float* W_ih   = (const float*)d_in[3];
  const float* W_hh   = (const float*)d_in[4];
  const float* b_lstm = (const float*)d_in[5];
  const float* W_out  = (const float*)d_in[6];
  const float* b_out  = (const float*)d_in[7];
  const float* W_gap  = (const float*)d_in[8];
  const float* b_gap  = (const float*)d_in[9];
  float* out = (float*)d_out;

  char* ws = (char*)d_ws;
  const size_t OFF_TABLE = 0;                        // 22*2048*4 = 180224
  const size_t OFF_WSWZ  = 184320;                   // 2MB bf16 swizzled W_hh
  const size_t OFF_HSWZ  = OFF_WSWZ + 2097152;       // 2 x 64KB bf16 swizzled h
  const size_t OFF_CBUF  = OFF_HSWZ + 131072;        // 32*1024*4 = 128KB
  const size_t OFF_HS    = OFF_CBUF + 131072;        // 512*64*512*4 = 64MB
  const size_t OFF_Z     = OFF_HS + 67108864;        // 64MB
  const size_t OFF_THETA = OFF_Z + 67108864;         // 32MB
  const size_t OFF_ZMEAN = OFF_THETA + 33554432;     // 128KB
  const size_t OFF_AOUT  = OFF_ZMEAN + 131072;       // 128B
  float* table = (float*)(ws + OFF_TABLE);
  unsigned short* Wswz = (unsigned short*)(ws + OFF_WSWZ);
  unsigned short* hswz = (unsigned short*)(ws + OFF_HSWZ);
  float* cbuf  = (float*)(ws + OFF_CBUF);
  float* hs    = (float*)(ws + OFF_HS);
  float* z     = (float*)(ws + OFF_Z);
  float* theta = (float*)(ws + OFF_THETA);
  float* zmean = (float*)(ws + OFF_ZMEAN);
  float* Aout  = (float*)(ws + OFF_AOUT);

  hipMemsetAsync(hswz, 0, 65536, stream);            // h(0) = 0 (buffer 0)
  hipMemsetAsync(cbuf, 0, 131072, stream);           // c(0) = 0

  table_k<<<dim3(8,22), 256, 0, stream>>>(emb, W_ih, b_lstm, table);
  wprep_k<<<2048, 64, 0, stream>>>(W_hh, Wswz);
  for(int s=0;s<TSEQ;s++){
    const unsigned short* h_in  = hswz + (size_t)(s&1)*32768;
    unsigned short*       h_out = hswz + (size_t)((s+1)&1)*32768;
    lstm_mfma<<<32, 512, 0, stream>>>(x, y, table, Wswz, h_in, h_out, cbuf, hs, s);
  }
  zproj_k<<<dim3(512,8), 256, 0, stream>>>(hs, W_out, b_out, z);
  theta_k<<<dim3(8,8,32), 256, 0, stream>>>(z, theta);
  mean_k<<<64, 256, 0, stream>>>(z, zmean);
  gap_k<<<32, 256, 0, stream>>>(zmean, W_gap, b_gap, Aout);
  nw_k<<<32, 64, 0, stream>>>(theta, Aout, out);
}